// Round 12
// baseline (528.794 us; speedup 1.0000x reference)
//
#include <hip/hip_runtime.h>
#include <hip/hip_fp16.h>
#include <math.h>

#define TPB 256
#define SCAN_CHUNK 1024
#define NBLK_LAYER 2048
#define NGROUPS (NBLK_LAYER * 8)
#define NBLK_TEAM 2048  // 8 teams x 256 member-blocks

struct alignas(16) half8 { __half h[8]; };

// ---------------------------------------------------------------------------
// prep: zero BN stat accumulators (zcount floats); compute state branch
// sx = relu(states@sw+sb), fold into c2[c] = a1b[c] + sum_k sx[k]*a1w[32+k][c]
// ---------------------------------------------------------------------------
__global__ __launch_bounds__(256) void prep_kernel(
    const float* __restrict__ states, const float* __restrict__ sw,
    const float* __restrict__ sb, const float* __restrict__ a1w,
    const float* __restrict__ a1b, float* __restrict__ stats,
    float* __restrict__ c2, int zcount) {
  int t = threadIdx.x;
  for (int j = t; j < zcount; j += 256) stats[j] = 0.0f;
  __shared__ float sx[16];
  if (t < 16) {
    float acc = sb[t];
#pragma unroll
    for (int k = 0; k < 7; ++k) acc += states[k] * sw[k * 16 + t];
    sx[t] = fmaxf(acc, 0.0f);
  }
  __syncthreads();
  if (t < 32) {
    float acc = a1b[t];
#pragma unroll
    for (int k = 0; k < 16; ++k) acc += sx[k] * a1w[(32 + k) * 32 + t];
    c2[t] = acc;
  }
}

// ---------------------------------------------------------------------------
// CSR build. hist/scatter are XCD-partitioned by dst range (blockIdx&7).
// ---------------------------------------------------------------------------
__global__ __launch_bounds__(256) void hist3_k(const int* __restrict__ dst,
                                               int* __restrict__ cnt, int E,
                                               int N) {
  int team = blockIdx.x & 7;
  int member = blockIdx.x >> 3;
  int n8 = (N + 7) >> 3;
  int lo = team * n8;
  int hi = lo + n8 < N ? lo + n8 : N;
  int stride = (NBLK_TEAM >> 3) * TPB;
  for (int e = member * TPB + threadIdx.x; e < E; e += stride) {
    int d = dst[e];
    if (d >= lo && d < hi) atomicAdd(&cnt[d], 1);
  }
}

__global__ __launch_bounds__(256) void scan1_k(const int* __restrict__ cnt,
                                               int* __restrict__ pre,
                                               int* __restrict__ bsum, int N) {
  __shared__ int lds[256];
  int b = blockIdx.x, t = threadIdx.x;
  int base = b * SCAN_CHUNK + t * 4;
  int c0 = (base + 0 < N) ? cnt[base + 0] : 0;
  int c1 = (base + 1 < N) ? cnt[base + 1] : 0;
  int c2 = (base + 2 < N) ? cnt[base + 2] : 0;
  int c3 = (base + 3 < N) ? cnt[base + 3] : 0;
  int s = c0 + c1 + c2 + c3;
  lds[t] = s;
  __syncthreads();
  int val = s;
  for (int off = 1; off < 256; off <<= 1) {
    int add = (t >= off) ? lds[t - off] : 0;
    __syncthreads();
    val += add;
    lds[t] = val;
    __syncthreads();
  }
  int excl = val - s;
  if (base + 0 < N) pre[base + 0] = excl;
  if (base + 1 < N) pre[base + 1] = excl + c0;
  if (base + 2 < N) pre[base + 2] = excl + c0 + c1;
  if (base + 3 < N) pre[base + 3] = excl + c0 + c1 + c2;
  if (t == 255) bsum[b] = val;
}

__global__ __launch_bounds__(512) void scan2_k(int* __restrict__ bsum, int nb) {
  __shared__ int lds[512];
  int t = threadIdx.x;
  int v = (t < nb) ? bsum[t] : 0;
  lds[t] = v;
  __syncthreads();
  int val = v;
  for (int off = 1; off < 512; off <<= 1) {
    int add = (t >= off) ? lds[t - off] : 0;
    __syncthreads();
    val += add;
    lds[t] = val;
    __syncthreads();
  }
  if (t < nb) bsum[t] = val - v;
}

__global__ __launch_bounds__(256) void scan3_k(int* __restrict__ pre,
                                               int* __restrict__ cursor,
                                               const int* __restrict__ bsum,
                                               int N, int E) {
  int i = blockIdx.x * TPB + threadIdx.x;
  if (i == 0) pre[N] = E;
  if (i >= N) return;
  int v = pre[i] + bsum[i >> 10];
  pre[i] = v;
  cursor[i] = v;
}

__global__ __launch_bounds__(256) void scatter3_k(
    const int* __restrict__ src, const int* __restrict__ dst,
    const float* __restrict__ ea, int* __restrict__ cursor,
    int2* __restrict__ pe, int E, int N) {
  int team = blockIdx.x & 7;
  int member = blockIdx.x >> 3;
  int n8 = (N + 7) >> 3;
  int lo = team * n8;
  int hi = lo + n8 < N ? lo + n8 : N;
  int stride = (NBLK_TEAM >> 3) * TPB;
  for (int e = member * TPB + threadIdx.x; e < E; e += stride) {
    int d = dst[e];
    if (d >= lo && d < hi) {
      int p = atomicAdd(&cursor[d], 1);
      pe[p] = make_int2(src[e], __float_as_int(ea[e]));
    }
  }
}

// ---------------------------------------------------------------------------
// layer 1 fused: gather x (d=4) + GINE + matmul(4x32) + BN stats.
// (round-6 structure; z stored as fp16)
// ---------------------------------------------------------------------------
__global__ __launch_bounds__(256) void layer1_k(
    const int* __restrict__ rowptr, const int2* __restrict__ pe,
    const float* __restrict__ x, const float* __restrict__ elw,
    const float* __restrict__ elb, const float* __restrict__ w,
    const float* __restrict__ b, const float* __restrict__ epsp,
    __half* __restrict__ zh, float* __restrict__ ostats, int N) {
  const int tid = threadIdx.x;
  const int c = tid & 31;
  const int group0 = blockIdx.x * 8 + (tid >> 5);
  float wc0 = w[0 * 32 + c], wc1 = w[1 * 32 + c], wc2 = w[2 * 32 + c],
        wc3 = w[3 * 32 + c];
  float bc = b[c];
  float w0 = elw[0], w1 = elw[1], w2 = elw[2], w3 = elw[3];
  float e0 = elb[0], e1 = elb[1], e2 = elb[2], e3 = elb[3];
  float one_eps = 1.0f + epsp[0];
  float sl = 0.f, sq = 0.f;
  for (int i = group0; i < N; i += NGROUPS) {
    int p0 = rowptr[i], p1 = rowptr[i + 1];
    float a0 = 0.f, a1 = 0.f, a2 = 0.f, a3 = 0.f;
    for (int p = p0 + c; p < p1; p += 32) {
      int2 e = pe[p];
      float a = __int_as_float(e.y);
      float4 xv = *reinterpret_cast<const float4*>(x + (size_t)e.x * 4);
      a0 += fmaxf(xv.x + fmaf(a, w0, e0), 0.f);
      a1 += fmaxf(xv.y + fmaf(a, w1, e1), 0.f);
      a2 += fmaxf(xv.z + fmaf(a, w2, e2), 0.f);
      a3 += fmaxf(xv.w + fmaf(a, w3, e3), 0.f);
    }
#pragma unroll
    for (int off = 16; off; off >>= 1) {
      a0 += __shfl_xor(a0, off, 32);
      a1 += __shfl_xor(a1, off, 32);
      a2 += __shfl_xor(a2, off, 32);
      a3 += __shfl_xor(a3, off, 32);
    }
    float4 xv = *reinterpret_cast<const float4*>(x + (size_t)i * 4);
    float h0 = fmaf(one_eps, xv.x, a0);
    float h1 = fmaf(one_eps, xv.y, a1);
    float h2 = fmaf(one_eps, xv.z, a2);
    float h3 = fmaf(one_eps, xv.w, a3);
    float zv = bc;
    zv = fmaf(h0, wc0, zv);
    zv = fmaf(h1, wc1, zv);
    zv = fmaf(h2, wc2, zv);
    zv = fmaf(h3, wc3, zv);
    zh[(size_t)i * 32 + c] = __float2half(zv);
    sl += zv;
    sq = fmaf(zv, zv, sq);
  }
  __shared__ float rs[256], rq[256];
  rs[tid] = sl;
  rq[tid] = sq;
  __syncthreads();
  if (tid < 32) {
    float a = 0.f, qq = 0.f;
#pragma unroll
    for (int g = 0; g < 8; ++g) {
      a += rs[g * 32 + tid];
      qq += rq[g * 32 + tid];
    }
    int slot = blockIdx.x & 7;
    atomicAdd(&ostats[slot * 32 + tid], a);
    atomicAdd(&ostats[256 + slot * 32 + tid], qq);
  }
}

// ---------------------------------------------------------------------------
// layers 2,3 fused — 16-LANE-PER-NODE variant: each wave64 carries 4
// independent node gather chains (lane owns 2 adjacent channels, __half2
// loads: 16 lanes x 4B = 64B coalesced row). Doubles outstanding gather
// chains per wave vs the 32-lane version WITHOUT masked load batching
// (which regressed in r7/r8/r9); each chain keeps the plain serial loop.
// BN(prev)+relu applied inline (fin fold). Matmul: half-wave reads its own
// groups' LDS stage (same-wave DS ordering, no barrier) with 32-lane
// float4-broadcast + wcol, as proven in r6-r11.
// ---------------------------------------------------------------------------
__global__ __launch_bounds__(256) void layerH_k(
    const int* __restrict__ rowptr, const int2* __restrict__ pe,
    const __half* __restrict__ zprev, const float* __restrict__ pstats,
    const float* __restrict__ pg, const float* __restrict__ pbt,
    const float* __restrict__ elw, const float* __restrict__ elb,
    const float* __restrict__ w, const float* __restrict__ b,
    const float* __restrict__ epsp, __half* __restrict__ zh,
    float* __restrict__ ostats, int N) {
  const int tid = threadIdx.x;
  const int lane = tid & 63;
  const int wid = tid >> 6;   // wave in block: 0..3
  const int g16 = lane >> 4;  // node-group within wave: 0..3
  const int c16 = lane & 15;  // lane within group
  const int c = lane & 31;    // matmul channel
  const int half = lane >> 5; // half-wave: 0..1

  __shared__ float sscale[32], sshift[32];
  if (tid < 32) {
    float ps = 0.f, pq = 0.f;
#pragma unroll
    for (int s = 0; s < 8; ++s) {
      ps += pstats[s * 32 + tid];
      pq += pstats[256 + s * 32 + tid];
    }
    float mu = ps / (float)N;
    float var = pq / (float)N - mu * mu;
    float sc = rsqrtf(var + 1e-5f) * pg[tid];
    sscale[tid] = sc;
    sshift[tid] = pbt[tid] - mu * sc;
  }
  __syncthreads();
  const int ch0 = 2 * c16, ch1 = ch0 + 1;
  const float scA = sscale[ch0], shA = sshift[ch0];
  const float scB = sscale[ch1], shB = sshift[ch1];
  const float ew0 = elw[ch0], eb0 = elb[ch0];
  const float ew1 = elw[ch1], eb1 = elb[ch1];
  float wcol[32];
#pragma unroll
  for (int k = 0; k < 32; ++k) wcol[k] = w[k * 32 + c];
  const float bc = b[c];
  const float one_eps = 1.0f + epsp[0];
  float sl = 0.f, sq = 0.f;
  __shared__ float hlds[4][4][32];
  const int waveBase = (blockIdx.x * 4 + wid) * 4;
  const int STRIDE = NBLK_LAYER * 16;  // blocks * 4 waves * 4 nodes
  for (int iBase = waveBase; iBase < N; iBase += STRIDE) {
    const int i = iBase + g16;
    const bool valid = i < N;
    float hh0 = 0.f, hh1 = 0.f;
    if (valid) {
      int p0 = rowptr[i], p1 = rowptr[i + 1];
      __half2 zs =
          *reinterpret_cast<const __half2*>(zprev + (size_t)i * 32 + ch0);
      float hs0 = fmaxf(fmaf(scA, __half2float(zs.x), shA), 0.f);
      float hs1 = fmaxf(fmaf(scB, __half2float(zs.y), shB), 0.f);
      float acc0 = 0.f, acc1 = 0.f;
      for (int p = p0; p < p1; ++p) {
        int2 e = pe[p];
        __half2 hz =
            *reinterpret_cast<const __half2*>(zprev + (size_t)e.x * 32 + ch0);
        float eaf = __int_as_float(e.y);
        float t0 = fmaxf(fmaf(scA, __half2float(hz.x), shA), 0.f);
        float t1 = fmaxf(fmaf(scB, __half2float(hz.y), shB), 0.f);
        acc0 += fmaxf(t0 + fmaf(eaf, ew0, eb0), 0.f);
        acc1 += fmaxf(t1 + fmaf(eaf, ew1, eb1), 0.f);
      }
      hh0 = fmaf(one_eps, hs0, acc0);
      hh1 = fmaf(one_eps, hs1, acc1);
    }
    *reinterpret_cast<float2*>(&hlds[wid][g16][ch0]) = make_float2(hh0, hh1);
    // matmul: half-wave h processes nodes 2*half, 2*half+1 (its own groups'
    // staged data -> same-wave DS ordering, no barrier needed)
#pragma unroll
    for (int u = 0; u < 2; ++u) {
      int nn = 2 * half + u;
      int inode = iBase + nn;
      if (inode < N) {
        float zv = bc;
        const float4* hp = reinterpret_cast<const float4*>(&hlds[wid][nn][0]);
#pragma unroll
        for (int kk = 0; kk < 8; ++kk) {
          float4 h4 = hp[kk];
          zv = fmaf(h4.x, wcol[kk * 4 + 0], zv);
          zv = fmaf(h4.y, wcol[kk * 4 + 1], zv);
          zv = fmaf(h4.z, wcol[kk * 4 + 2], zv);
          zv = fmaf(h4.w, wcol[kk * 4 + 3], zv);
        }
        zh[(size_t)inode * 32 + c] = __float2half(zv);
        sl += zv;
        sq = fmaf(zv, zv, sq);
      }
    }
  }
  __shared__ float rs[256], rq[256];
  rs[tid] = sl;
  rq[tid] = sq;
  __syncthreads();
  if (tid < 32) {
    float a = 0.f, qq = 0.f;
#pragma unroll
    for (int g = 0; g < 8; ++g) {
      a += rs[g * 32 + tid];
      qq += rq[g * 32 + tid];
    }
    int slot = blockIdx.x & 7;
    atomicAdd(&ostats[slot * 32 + tid], a);
    atomicAdd(&ostats[256 + slot * 32 + tid], qq);
  }
}

// ---------------------------------------------------------------------------
// head: BN3+relu, a1 = relu(y@a1w + c2), logits = a1@a2w + a2b, softmax.
// Logits via partial-sum transpose: lane c -> logit j=c&7, k-octet g=c>>3.
// (round-6 structure; z read as fp16)
// ---------------------------------------------------------------------------
__global__ __launch_bounds__(256) void head_k(
    const __half* __restrict__ zh, const float* __restrict__ pstats,
    const float* __restrict__ pg, const float* __restrict__ pbt,
    const float* __restrict__ a1w, const float* __restrict__ c2,
    const float* __restrict__ a2w, const float* __restrict__ a2b,
    float* __restrict__ out, int N) {
  const int tid = threadIdx.x;
  const int c = tid & 31;
  const int gib = tid >> 5;
  const int group0 = blockIdx.x * 8 + gib;
  float ps = 0.f, pq = 0.f;
#pragma unroll
  for (int s = 0; s < 8; ++s) {
    ps += pstats[s * 32 + c];
    pq += pstats[256 + s * 32 + c];
  }
  float mu = ps / (float)N;
  float var = pq / (float)N - mu * mu;
  float scale = rsqrtf(var + 1e-5f) * pg[c];
  float shift = pbt[c] - mu * scale;
  float wcol[32];
#pragma unroll
  for (int k = 0; k < 32; ++k) wcol[k] = a1w[k * 32 + c];
  float c2c = c2[c];
  const int j = c & 7;
  const int g = c >> 3;
  float w2r[8];
#pragma unroll
  for (int u = 0; u < 8; ++u)
    w2r[u] = (j < 6) ? a2w[(8 * g + u) * 6 + j] : 0.f;
  float bj = (j < 6) ? a2b[j] : 0.f;
  __shared__ float ylds[256];
  __shared__ float alds[256];
  __shared__ float llds[64];
  for (int i = group0; i < N; i += NGROUPS) {
    float y =
        fmaxf(fmaf(scale, __half2float(zh[(size_t)i * 32 + c]), shift), 0.f);
    ylds[tid] = y;
    float a1 = c2c;
    const float4* yp = reinterpret_cast<const float4*>(&ylds[gib * 32]);
#pragma unroll
    for (int kk = 0; kk < 8; ++kk) {
      float4 y4 = yp[kk];
      a1 = fmaf(y4.x, wcol[kk * 4 + 0], a1);
      a1 = fmaf(y4.y, wcol[kk * 4 + 1], a1);
      a1 = fmaf(y4.z, wcol[kk * 4 + 2], a1);
      a1 = fmaf(y4.w, wcol[kk * 4 + 3], a1);
    }
    a1 = fmaxf(a1, 0.f);
    alds[tid] = a1;
    const float4* ap =
        reinterpret_cast<const float4*>(&alds[gib * 32 + g * 8]);
    float4 a4a = ap[0];
    float4 a4b = ap[1];
    float l = a4a.x * w2r[0];
    l = fmaf(a4a.y, w2r[1], l);
    l = fmaf(a4a.z, w2r[2], l);
    l = fmaf(a4a.w, w2r[3], l);
    l = fmaf(a4b.x, w2r[4], l);
    l = fmaf(a4b.y, w2r[5], l);
    l = fmaf(a4b.z, w2r[6], l);
    l = fmaf(a4b.w, w2r[7], l);
    l += __shfl_xor(l, 8, 32);
    l += __shfl_xor(l, 16, 32);
    l += bj;  // j>=6 lanes: l stays exactly 0 (w2r zeros) -> safe pad
    llds[gib * 8 + j] = l;
    const float4* lp = reinterpret_cast<const float4*>(&llds[gib * 8]);
    float4 L0 = lp[0];
    float4 L1 = lp[1];
    float mx =
        fmaxf(fmaxf(fmaxf(L0.x, L0.y), fmaxf(L0.z, L0.w)), fmaxf(L1.x, L1.y));
    float e0 = __expf(L0.x - mx), e1 = __expf(L0.y - mx),
          e2 = __expf(L0.z - mx), e3 = __expf(L0.w - mx),
          e4 = __expf(L1.x - mx), e5 = __expf(L1.y - mx);
    float inv = 1.0f / (e0 + e1 + e2 + e3 + e4 + e5);
    if (c < 6) {
      float v = e0;
      v = (c == 1) ? e1 : v;
      v = (c == 2) ? e2 : v;
      v = (c == 3) ? e3 : v;
      v = (c == 4) ? e4 : v;
      v = (c == 5) ? e5 : v;
      out[(size_t)i * 6 + c] = v * inv;
    }
  }
}

// ---------------------------------------------------------------------------
// fallback kernels (atomic scatter path) — used only if workspace too small
// ---------------------------------------------------------------------------
__global__ __launch_bounds__(256) void edge_d4(
    const int* __restrict__ src, const int* __restrict__ dst,
    const float* __restrict__ ea, const float* __restrict__ x,
    const float* __restrict__ elw, const float* __restrict__ elb,
    float* __restrict__ agg, int E) {
  int e = blockIdx.x * TPB + threadIdx.x;
  if (e >= E) return;
  int s = src[e], d = dst[e];
  float a = ea[e];
  float4 xv = *reinterpret_cast<const float4*>(x + (size_t)s * 4);
  float m0 = fmaxf(xv.x + a * elw[0] + elb[0], 0.0f);
  float m1 = fmaxf(xv.y + a * elw[1] + elb[1], 0.0f);
  float m2 = fmaxf(xv.z + a * elw[2] + elb[2], 0.0f);
  float m3 = fmaxf(xv.w + a * elw[3] + elb[3], 0.0f);
  float* ap = agg + (size_t)d * 32;
  atomicAdd(ap + 0, m0);
  atomicAdd(ap + 1, m1);
  atomicAdd(ap + 2, m2);
  atomicAdd(ap + 3, m3);
}

__global__ __launch_bounds__(256) void edge_d32(
    const int* __restrict__ src, const int* __restrict__ dst,
    const float* __restrict__ ea, const float* __restrict__ x,
    const float* __restrict__ elw, const float* __restrict__ elb,
    float* __restrict__ agg, int E) {
  int tid = blockIdx.x * TPB + threadIdx.x;
  int e = tid >> 5;
  int c = tid & 31;
  if (e >= E) return;
  int s = src[e], d = dst[e];
  float a = ea[e];
  float m = fmaxf(x[(size_t)s * 32 + c] + a * elw[c] + elb[c], 0.0f);
  atomicAdd(agg + (size_t)d * 32 + c, m);
}

template <int DIN>
__global__ __launch_bounds__(256) void node_a(
    const float* __restrict__ x, float* aggz, const float* __restrict__ w,
    const float* __restrict__ b, const float* __restrict__ epsp,
    float* __restrict__ ssum, float* __restrict__ ssq, int N) {
  int i = blockIdx.x * TPB + threadIdx.x;
  float zv[32];
  if (i < N) {
    float one_eps = 1.0f + epsp[0];
    float h[DIN];
    if constexpr (DIN == 4) {
      float4 xv = *reinterpret_cast<const float4*>(x + (size_t)i * 4);
      float4 av = *reinterpret_cast<const float4*>(aggz + (size_t)i * 32);
      h[0] = one_eps * xv.x + av.x;
      h[1] = one_eps * xv.y + av.y;
      h[2] = one_eps * xv.z + av.z;
      h[3] = one_eps * xv.w + av.w;
    } else {
#pragma unroll
      for (int k0 = 0; k0 < 32; k0 += 4) {
        float4 xv = *reinterpret_cast<const float4*>(x + (size_t)i * 32 + k0);
        float4 av =
            *reinterpret_cast<const float4*>(aggz + (size_t)i * 32 + k0);
        h[k0 + 0] = one_eps * xv.x + av.x;
        h[k0 + 1] = one_eps * xv.y + av.y;
        h[k0 + 2] = one_eps * xv.z + av.z;
        h[k0 + 3] = one_eps * xv.w + av.w;
      }
    }
#pragma unroll
    for (int c = 0; c < 32; ++c) zv[c] = b[c];
#pragma unroll
    for (int k = 0; k < DIN; ++k)
#pragma unroll
      for (int c = 0; c < 32; ++c) zv[c] = fmaf(h[k], w[k * 32 + c], zv[c]);
#pragma unroll
    for (int c0 = 0; c0 < 32; c0 += 4) {
      float4 o = make_float4(zv[c0], zv[c0 + 1], zv[c0 + 2], zv[c0 + 3]);
      *reinterpret_cast<float4*>(aggz + (size_t)i * 32 + c0) = o;
    }
  } else {
#pragma unroll
    for (int c = 0; c < 32; ++c) zv[c] = 0.0f;
  }
  __shared__ float ls[32], lq[32];
  if (threadIdx.x < 32) {
    ls[threadIdx.x] = 0.0f;
    lq[threadIdx.x] = 0.0f;
  }
  __syncthreads();
#pragma unroll
  for (int c = 0; c < 32; ++c) {
    float v = zv[c];
    float q = zv[c] * zv[c];
#pragma unroll
    for (int off = 32; off > 0; off >>= 1) {
      v += __shfl_xor(v, off, 64);
      q += __shfl_xor(q, off, 64);
    }
    if ((threadIdx.x & 63) == 0) {
      atomicAdd(&ls[c], v);
      atomicAdd(&lq[c], q);
    }
  }
  __syncthreads();
  if (threadIdx.x < 32) {
    atomicAdd(&ssum[threadIdx.x], ls[threadIdx.x]);
    atomicAdd(&ssq[threadIdx.x], lq[threadIdx.x]);
  }
}

__global__ __launch_bounds__(256) void node_b(
    const float* __restrict__ z, const float* __restrict__ ssum,
    const float* __restrict__ ssq, const float* __restrict__ g,
    const float* __restrict__ bt, float* __restrict__ out, int N) {
  __shared__ float sscale[32], sshift[32];
  if (threadIdx.x < 32) {
    int c = threadIdx.x;
    float mu = ssum[c] / (float)N;
    float var = ssq[c] / (float)N - mu * mu;
    float inv = 1.0f / sqrtf(var + 1e-5f);
    float sc = inv * g[c];
    sscale[c] = sc;
    sshift[c] = bt[c] - mu * sc;
  }
  __syncthreads();
  int i = blockIdx.x * TPB + threadIdx.x;
  if (i >= N) return;
#pragma unroll
  for (int c0 = 0; c0 < 32; c0 += 4) {
    float4 zv = *reinterpret_cast<const float4*>(z + (size_t)i * 32 + c0);
    float4 o;
    o.x = fmaxf(zv.x * sscale[c0 + 0] + sshift[c0 + 0], 0.0f);
    o.y = fmaxf(zv.y * sscale[c0 + 1] + sshift[c0 + 1], 0.0f);
    o.z = fmaxf(zv.z * sscale[c0 + 2] + sshift[c0 + 2], 0.0f);
    o.w = fmaxf(zv.w * sscale[c0 + 3] + sshift[c0 + 3], 0.0f);
    *reinterpret_cast<float4*>(out + (size_t)i * 32 + c0) = o;
  }
}

__global__ __launch_bounds__(256) void node_b3_head(
    const float* __restrict__ z, const float* __restrict__ ssum,
    const float* __restrict__ ssq, const float* __restrict__ g,
    const float* __restrict__ bt, const float* __restrict__ a1w,
    const float* __restrict__ c2, const float* __restrict__ a2w,
    const float* __restrict__ a2b, float* __restrict__ out, int N) {
  __shared__ float sscale[32], sshift[32];
  if (threadIdx.x < 32) {
    int c = threadIdx.x;
    float mu = ssum[c] / (float)N;
    float var = ssq[c] / (float)N - mu * mu;
    float inv = 1.0f / sqrtf(var + 1e-5f);
    float sc = inv * g[c];
    sscale[c] = sc;
    sshift[c] = bt[c] - mu * sc;
  }
  __syncthreads();
  int i = blockIdx.x * TPB + threadIdx.x;
  if (i >= N) return;
  float y[32];
#pragma unroll
  for (int c0 = 0; c0 < 32; c0 += 4) {
    float4 zv = *reinterpret_cast<const float4*>(z + (size_t)i * 32 + c0);
    y[c0 + 0] = fmaxf(zv.x * sscale[c0 + 0] + sshift[c0 + 0], 0.0f);
    y[c0 + 1] = fmaxf(zv.y * sscale[c0 + 1] + sshift[c0 + 1], 0.0f);
    y[c0 + 2] = fmaxf(zv.z * sscale[c0 + 2] + sshift[c0 + 2], 0.0f);
    y[c0 + 3] = fmaxf(zv.w * sscale[c0 + 3] + sshift[c0 + 3], 0.0f);
  }
  float a1[32];
#pragma unroll
  for (int c = 0; c < 32; ++c) a1[c] = c2[c];
#pragma unroll
  for (int k = 0; k < 32; ++k)
#pragma unroll
    for (int c = 0; c < 32; ++c) a1[c] = fmaf(y[k], a1w[k * 32 + c], a1[c]);
#pragma unroll
  for (int c = 0; c < 32; ++c) a1[c] = fmaxf(a1[c], 0.0f);
  float lg[6];
#pragma unroll
  for (int j = 0; j < 6; ++j) lg[j] = a2b[j];
#pragma unroll
  for (int k = 0; k < 32; ++k)
#pragma unroll
    for (int j = 0; j < 6; ++j) lg[j] = fmaf(a1[k], a2w[k * 6 + j], lg[j]);
  float mx = lg[0];
#pragma unroll
  for (int j = 1; j < 6; ++j) mx = fmaxf(mx, lg[j]);
  float s = 0.0f;
#pragma unroll
  for (int j = 0; j < 6; ++j) {
    lg[j] = expf(lg[j] - mx);
    s += lg[j];
  }
  float rs = 1.0f / s;
#pragma unroll
  for (int j = 0; j < 6; ++j) out[(size_t)i * 6 + j] = lg[j] * rs;
}

// ---------------------------------------------------------------------------
extern "C" void kernel_launch(void* const* d_in, const int* in_sizes, int n_in,
                              void* d_out, int out_size, void* d_ws,
                              size_t ws_size, hipStream_t stream) {
  const float* states = (const float*)d_in[0];
  const float* x = (const float*)d_in[1];
  const int* ei = (const int*)d_in[2];
  const float* ea = (const float*)d_in[3];
  const float* eps1 = (const float*)d_in[5];
  const float* elw1 = (const float*)d_in[6];
  const float* elb1 = (const float*)d_in[7];
  const float* w1 = (const float*)d_in[8];
  const float* b1 = (const float*)d_in[9];
  const float* g1 = (const float*)d_in[10];
  const float* bt1 = (const float*)d_in[11];
  const float* eps2 = (const float*)d_in[12];
  const float* elw2 = (const float*)d_in[13];
  const float* elb2 = (const float*)d_in[14];
  const float* w2 = (const float*)d_in[15];
  const float* b2 = (const float*)d_in[16];
  const float* g2 = (const float*)d_in[17];
  const float* bt2 = (const float*)d_in[18];
  const float* eps3 = (const float*)d_in[19];
  const float* elw3 = (const float*)d_in[20];
  const float* elb3 = (const float*)d_in[21];
  const float* w3 = (const float*)d_in[22];
  const float* b3 = (const float*)d_in[23];
  const float* g3 = (const float*)d_in[24];
  const float* bt3 = (const float*)d_in[25];
  const float* sw = (const float*)d_in[26];
  const float* sb = (const float*)d_in[27];
  const float* a1w = (const float*)d_in[28];
  const float* a1b = (const float*)d_in[29];
  const float* a2w = (const float*)d_in[30];
  const float* a2b = (const float*)d_in[31];

  int N = in_sizes[1] / 4;
  int E = in_sizes[3];
  const int* src = ei;
  const int* dst = ei + E;
  float* out = (float*)d_out;

  // workspace layout (CSR path), byte-based:
  //   zhA  : N*32 half (64N bytes)   z1, z3
  //   zhB  : N*32 half (64N bytes)   z2
  //   stats: 1536 f32 ; c2: 32 f32
  //   pe   : E int2 ; rowptr: N+1 ; cursor: N ; bsum: <=512
  char* wsb = (char*)d_ws;
  __half* zhA = (__half*)wsb;
  __half* zhB = (__half*)(wsb + (size_t)64 * N);
  float* stats = (float*)(wsb + (size_t)128 * N);
  float* c2csr = stats + 1536;
  int2* pe = (int2*)(c2csr + 32);
  int* rowptr = (int*)(pe + (size_t)E);
  int* cursor = rowptr + (N + 1);
  int* bsum = cursor + N;

  int nblkN = (N + TPB - 1) / TPB;
  int nblkE = (E + TPB - 1) / TPB;
  int nb = (N + SCAN_CHUNK - 1) / SCAN_CHUNK;

  size_t need = (size_t)128 * N + 6272 + (size_t)8 * E + (size_t)4 * (N + 1) +
                (size_t)4 * N + 2048;

  if (ws_size >= need && nb <= 512) {
    prep_kernel<<<1, TPB, 0, stream>>>(states, sw, sb, a1w, a1b, stats, c2csr,
                                       1536);
    // CSR build (hist/scatter XCD-partitioned by dst range)
    hipMemsetAsync(cursor, 0, (size_t)N * sizeof(int), stream);
    hist3_k<<<NBLK_TEAM, TPB, 0, stream>>>(dst, cursor, E, N);
    scan1_k<<<nb, TPB, 0, stream>>>(cursor, rowptr, bsum, N);
    scan2_k<<<1, 512, 0, stream>>>(bsum, nb);
    scan3_k<<<nblkN, TPB, 0, stream>>>(rowptr, cursor, bsum, N, E);
    scatter3_k<<<NBLK_TEAM, TPB, 0, stream>>>(src, dst, ea, cursor, pe, E, N);

    layer1_k<<<NBLK_LAYER, TPB, 0, stream>>>(rowptr, pe, x, elw1, elb1, w1, b1,
                                             eps1, zhA, stats + 0, N);
    layerH_k<<<NBLK_LAYER, TPB, 0, stream>>>(rowptr, pe, zhA, stats + 0, g1,
                                             bt1, elw2, elb2, w2, b2, eps2,
                                             zhB, stats + 512, N);
    layerH_k<<<NBLK_LAYER, TPB, 0, stream>>>(rowptr, pe, zhB, stats + 512, g2,
                                             bt2, elw3, elb3, w3, b3, eps3,
                                             zhA, stats + 1024, N);
    head_k<<<NBLK_LAYER, TPB, 0, stream>>>(zhA, stats + 1024, g3, bt3, a1w,
                                           c2csr, a2w, a2b, out, N);
  } else {
    // fallback: atomic scatter path (f32 layout over d_ws)
    float* zA = (float*)d_ws;
    float* zB = zA + (size_t)N * 32;
    float* statsFB = zB + (size_t)N * 32;
    float* c2fb = statsFB + 192;
    prep_kernel<<<1, TPB, 0, stream>>>(states, sw, sb, a1w, a1b, statsFB, c2fb,
                                       192);
    size_t aggBytes = (size_t)N * 32 * sizeof(float);
    int nblkE32 = (int)(((long long)E * 32 + TPB - 1) / TPB);
    hipMemsetAsync(zA, 0, aggBytes, stream);
    edge_d4<<<nblkE, TPB, 0, stream>>>(src, dst, ea, x, elw1, elb1, zA, E);
    node_a<4><<<nblkN, TPB, 0, stream>>>(x, zA, w1, b1, eps1, statsFB + 0,
                                         statsFB + 32, N);
    node_b<<<nblkN, TPB, 0, stream>>>(zA, statsFB + 0, statsFB + 32, g1, bt1,
                                      zB, N);
    hipMemsetAsync(zA, 0, aggBytes, stream);
    edge_d32<<<nblkE32, TPB, 0, stream>>>(src, dst, ea, zB, elw2, elb2, zA, E);
    node_a<32><<<nblkN, TPB, 0, stream>>>(zB, zA, w2, b2, eps2, statsFB + 64,
                                          statsFB + 96, N);
    node_b<<<nblkN, TPB, 0, stream>>>(zA, statsFB + 64, statsFB + 96, g2, bt2,
                                      zB, N);
    hipMemsetAsync(zA, 0, aggBytes, stream);
    edge_d32<<<nblkE32, TPB, 0, stream>>>(src, dst, ea, zB, elw3, elb3, zA, E);
    node_a<32><<<nblkN, TPB, 0, stream>>>(zB, zA, w3, b3, eps3, statsFB + 128,
                                          statsFB + 160, N);
    node_b3_head<<<nblkN, TPB, 0, stream>>>(zA, statsFB + 128, statsFB + 160,
                                            g3, bt3, a1w, c2fb, a2w, a2b, out,
                                            N);
  }
}

// Round 13
// 485.457 us; speedup vs baseline: 1.0893x; 1.0893x over previous
//
#include <hip/hip_runtime.h>
#include <hip/hip_fp16.h>
#include <math.h>

#define TPB 256
#define SCAN_CHUNK 1024
#define NBLK_LAYER 2048
#define NGROUPS (NBLK_LAYER * 8)
#define NBLK_TEAM 2048  // 8 teams x 256 member-blocks

struct alignas(16) half8 { __half h[8]; };

// ---------------------------------------------------------------------------
// prep: zero BN stat accumulators (zcount floats); compute state branch
// sx = relu(states@sw+sb), fold into c2[c] = a1b[c] + sum_k sx[k]*a1w[32+k][c]
// ---------------------------------------------------------------------------
__global__ __launch_bounds__(256) void prep_kernel(
    const float* __restrict__ states, const float* __restrict__ sw,
    const float* __restrict__ sb, const float* __restrict__ a1w,
    const float* __restrict__ a1b, float* __restrict__ stats,
    float* __restrict__ c2, int zcount) {
  int t = threadIdx.x;
  for (int j = t; j < zcount; j += 256) stats[j] = 0.0f;
  __shared__ float sx[16];
  if (t < 16) {
    float acc = sb[t];
#pragma unroll
    for (int k = 0; k < 7; ++k) acc += states[k] * sw[k * 16 + t];
    sx[t] = fmaxf(acc, 0.0f);
  }
  __syncthreads();
  if (t < 32) {
    float acc = a1b[t];
#pragma unroll
    for (int k = 0; k < 16; ++k) acc += sx[k] * a1w[(32 + k) * 32 + t];
    c2[t] = acc;
  }
}

// ---------------------------------------------------------------------------
// CSR build. hist/scatter are XCD-partitioned by dst range (blockIdx&7).
// ---------------------------------------------------------------------------
__global__ __launch_bounds__(256) void hist3_k(const int* __restrict__ dst,
                                               int* __restrict__ cnt, int E,
                                               int N) {
  int team = blockIdx.x & 7;
  int member = blockIdx.x >> 3;
  int n8 = (N + 7) >> 3;
  int lo = team * n8;
  int hi = lo + n8 < N ? lo + n8 : N;
  int stride = (NBLK_TEAM >> 3) * TPB;
  for (int e = member * TPB + threadIdx.x; e < E; e += stride) {
    int d = dst[e];
    if (d >= lo && d < hi) atomicAdd(&cnt[d], 1);
  }
}

__global__ __launch_bounds__(256) void scan1_k(const int* __restrict__ cnt,
                                               int* __restrict__ pre,
                                               int* __restrict__ bsum, int N) {
  __shared__ int lds[256];
  int b = blockIdx.x, t = threadIdx.x;
  int base = b * SCAN_CHUNK + t * 4;
  int c0 = (base + 0 < N) ? cnt[base + 0] : 0;
  int c1 = (base + 1 < N) ? cnt[base + 1] : 0;
  int c2 = (base + 2 < N) ? cnt[base + 2] : 0;
  int c3 = (base + 3 < N) ? cnt[base + 3] : 0;
  int s = c0 + c1 + c2 + c3;
  lds[t] = s;
  __syncthreads();
  int val = s;
  for (int off = 1; off < 256; off <<= 1) {
    int add = (t >= off) ? lds[t - off] : 0;
    __syncthreads();
    val += add;
    lds[t] = val;
    __syncthreads();
  }
  int excl = val - s;
  if (base + 0 < N) pre[base + 0] = excl;
  if (base + 1 < N) pre[base + 1] = excl + c0;
  if (base + 2 < N) pre[base + 2] = excl + c0 + c1;
  if (base + 3 < N) pre[base + 3] = excl + c0 + c1 + c2;
  if (t == 255) bsum[b] = val;
}

__global__ __launch_bounds__(512) void scan2_k(int* __restrict__ bsum, int nb) {
  __shared__ int lds[512];
  int t = threadIdx.x;
  int v = (t < nb) ? bsum[t] : 0;
  lds[t] = v;
  __syncthreads();
  int val = v;
  for (int off = 1; off < 512; off <<= 1) {
    int add = (t >= off) ? lds[t - off] : 0;
    __syncthreads();
    val += add;
    lds[t] = val;
    __syncthreads();
  }
  if (t < nb) bsum[t] = val - v;
}

__global__ __launch_bounds__(256) void scan3_k(int* __restrict__ pre,
                                               int* __restrict__ cursor,
                                               const int* __restrict__ bsum,
                                               int N, int E) {
  int i = blockIdx.x * TPB + threadIdx.x;
  if (i == 0) pre[N] = E;
  if (i >= N) return;
  int v = pre[i] + bsum[i >> 10];
  pre[i] = v;
  cursor[i] = v;
}

__global__ __launch_bounds__(256) void scatter3_k(
    const int* __restrict__ src, const int* __restrict__ dst,
    const float* __restrict__ ea, int* __restrict__ cursor,
    int2* __restrict__ pe, int E, int N) {
  int team = blockIdx.x & 7;
  int member = blockIdx.x >> 3;
  int n8 = (N + 7) >> 3;
  int lo = team * n8;
  int hi = lo + n8 < N ? lo + n8 : N;
  int stride = (NBLK_TEAM >> 3) * TPB;
  for (int e = member * TPB + threadIdx.x; e < E; e += stride) {
    int d = dst[e];
    if (d >= lo && d < hi) {
      int p = atomicAdd(&cursor[d], 1);
      pe[p] = make_int2(src[e], __float_as_int(ea[e]));
    }
  }
}

// ---------------------------------------------------------------------------
// layer 1 fused: gather x (d=4) + GINE + matmul(4x32) + BN stats.
// (round-6 structure; z stored as fp16)
// ---------------------------------------------------------------------------
__global__ __launch_bounds__(256) void layer1_k(
    const int* __restrict__ rowptr, const int2* __restrict__ pe,
    const float* __restrict__ x, const float* __restrict__ elw,
    const float* __restrict__ elb, const float* __restrict__ w,
    const float* __restrict__ b, const float* __restrict__ epsp,
    __half* __restrict__ zh, float* __restrict__ ostats, int N) {
  const int tid = threadIdx.x;
  const int c = tid & 31;
  const int group0 = blockIdx.x * 8 + (tid >> 5);
  float wc0 = w[0 * 32 + c], wc1 = w[1 * 32 + c], wc2 = w[2 * 32 + c],
        wc3 = w[3 * 32 + c];
  float bc = b[c];
  float w0 = elw[0], w1 = elw[1], w2 = elw[2], w3 = elw[3];
  float e0 = elb[0], e1 = elb[1], e2 = elb[2], e3 = elb[3];
  float one_eps = 1.0f + epsp[0];
  float sl = 0.f, sq = 0.f;
  for (int i = group0; i < N; i += NGROUPS) {
    int p0 = rowptr[i], p1 = rowptr[i + 1];
    float a0 = 0.f, a1 = 0.f, a2 = 0.f, a3 = 0.f;
    for (int p = p0 + c; p < p1; p += 32) {
      int2 e = pe[p];
      float a = __int_as_float(e.y);
      float4 xv = *reinterpret_cast<const float4*>(x + (size_t)e.x * 4);
      a0 += fmaxf(xv.x + fmaf(a, w0, e0), 0.f);
      a1 += fmaxf(xv.y + fmaf(a, w1, e1), 0.f);
      a2 += fmaxf(xv.z + fmaf(a, w2, e2), 0.f);
      a3 += fmaxf(xv.w + fmaf(a, w3, e3), 0.f);
    }
#pragma unroll
    for (int off = 16; off; off >>= 1) {
      a0 += __shfl_xor(a0, off, 32);
      a1 += __shfl_xor(a1, off, 32);
      a2 += __shfl_xor(a2, off, 32);
      a3 += __shfl_xor(a3, off, 32);
    }
    float4 xv = *reinterpret_cast<const float4*>(x + (size_t)i * 4);
    float h0 = fmaf(one_eps, xv.x, a0);
    float h1 = fmaf(one_eps, xv.y, a1);
    float h2 = fmaf(one_eps, xv.z, a2);
    float h3 = fmaf(one_eps, xv.w, a3);
    float zv = bc;
    zv = fmaf(h0, wc0, zv);
    zv = fmaf(h1, wc1, zv);
    zv = fmaf(h2, wc2, zv);
    zv = fmaf(h3, wc3, zv);
    zh[(size_t)i * 32 + c] = __float2half(zv);
    sl += zv;
    sq = fmaf(zv, zv, sq);
  }
  __shared__ float rs[256], rq[256];
  rs[tid] = sl;
  rq[tid] = sq;
  __syncthreads();
  if (tid < 32) {
    float a = 0.f, qq = 0.f;
#pragma unroll
    for (int g = 0; g < 8; ++g) {
      a += rs[g * 32 + tid];
      qq += rq[g * 32 + tid];
    }
    int slot = blockIdx.x & 7;
    atomicAdd(&ostats[slot * 32 + tid], a);
    atomicAdd(&ostats[256 + slot * 32 + tid], qq);
  }
}

// ---------------------------------------------------------------------------
// layers 2,3 fused (round-6 loop structure; fin_k folded in):
// gather PRE-BN fp16 z rows of the previous layer and apply that layer's
// BN scale/shift + relu inline per element. Matmul via half-wave LDS stage
// + float4 broadcast reads (no barrier: stage area written/read by the same
// half-wave, DS ops in-order).
// NOTE: FOUR attempts to restructure the gather loop (r7 distant-pair, r8
// masked 4-batch, r9 while-prefetch, r12 16-lane-per-node) ALL regressed
// 20-80% with occupancy 78%->43-46%. The plain serial loop IS the optimum
// at source level; the limiter is the memory system's service rate for
// random 64B requests, which this loop already saturates.
// ---------------------------------------------------------------------------
__global__ __launch_bounds__(256) void layerH_k(
    const int* __restrict__ rowptr, const int2* __restrict__ pe,
    const __half* __restrict__ zprev, const float* __restrict__ pstats,
    const float* __restrict__ pg, const float* __restrict__ pbt,
    const float* __restrict__ elw, const float* __restrict__ elb,
    const float* __restrict__ w, const float* __restrict__ b,
    const float* __restrict__ epsp, __half* __restrict__ zh,
    float* __restrict__ ostats, int N) {
  const int tid = threadIdx.x;
  const int c = tid & 31;
  const int gib = tid >> 5;
  const int group0 = blockIdx.x * 8 + gib;
  float ps = 0.f, pq = 0.f;
#pragma unroll
  for (int s = 0; s < 8; ++s) {
    ps += pstats[s * 32 + c];
    pq += pstats[256 + s * 32 + c];
  }
  float mu = ps / (float)N;
  float var = pq / (float)N - mu * mu;
  float scale = rsqrtf(var + 1e-5f) * pg[c];
  float shift = pbt[c] - mu * scale;
  float wcol[32];
#pragma unroll
  for (int k = 0; k < 32; ++k) wcol[k] = w[k * 32 + c];
  float elwc = elw[c], elbc = elb[c], bc = b[c];
  float one_eps = 1.0f + epsp[0];
  float sl = 0.f, sq = 0.f;
  __shared__ float hlds[256];
  for (int i = group0; i < N; i += NGROUPS) {
    int p0 = rowptr[i], p1 = rowptr[i + 1];
    float hself =
        fmaxf(fmaf(scale, __half2float(zprev[(size_t)i * 32 + c]), shift), 0.f);
    float acc = 0.f;
    for (int p = p0; p < p1; ++p) {
      int2 e = pe[p];
      float hs = fmaxf(
          fmaf(scale, __half2float(zprev[(size_t)e.x * 32 + c]), shift), 0.f);
      acc += fmaxf(hs + fmaf(__int_as_float(e.y), elwc, elbc), 0.f);
    }
    float hh = fmaf(one_eps, hself, acc);
    hlds[tid] = hh;
    float zv = bc;
    const float4* hp = reinterpret_cast<const float4*>(&hlds[gib * 32]);
#pragma unroll
    for (int kk = 0; kk < 8; ++kk) {
      float4 h4 = hp[kk];
      zv = fmaf(h4.x, wcol[kk * 4 + 0], zv);
      zv = fmaf(h4.y, wcol[kk * 4 + 1], zv);
      zv = fmaf(h4.z, wcol[kk * 4 + 2], zv);
      zv = fmaf(h4.w, wcol[kk * 4 + 3], zv);
    }
    zh[(size_t)i * 32 + c] = __float2half(zv);
    sl += zv;
    sq = fmaf(zv, zv, sq);
  }
  __shared__ float rs[256], rq[256];
  rs[tid] = sl;
  rq[tid] = sq;
  __syncthreads();
  if (tid < 32) {
    float a = 0.f, qq = 0.f;
#pragma unroll
    for (int g = 0; g < 8; ++g) {
      a += rs[g * 32 + tid];
      qq += rq[g * 32 + tid];
    }
    int slot = blockIdx.x & 7;
    atomicAdd(&ostats[slot * 32 + tid], a);
    atomicAdd(&ostats[256 + slot * 32 + tid], qq);
  }
}

// ---------------------------------------------------------------------------
// head: BN3+relu, a1 = relu(y@a1w + c2), logits = a1@a2w + a2b, softmax.
// Logits via partial-sum transpose: lane c -> logit j=c&7, k-octet g=c>>3.
// (round-6 structure; z read as fp16)
// ---------------------------------------------------------------------------
__global__ __launch_bounds__(256) void head_k(
    const __half* __restrict__ zh, const float* __restrict__ pstats,
    const float* __restrict__ pg, const float* __restrict__ pbt,
    const float* __restrict__ a1w, const float* __restrict__ c2,
    const float* __restrict__ a2w, const float* __restrict__ a2b,
    float* __restrict__ out, int N) {
  const int tid = threadIdx.x;
  const int c = tid & 31;
  const int gib = tid >> 5;
  const int group0 = blockIdx.x * 8 + gib;
  float ps = 0.f, pq = 0.f;
#pragma unroll
  for (int s = 0; s < 8; ++s) {
    ps += pstats[s * 32 + c];
    pq += pstats[256 + s * 32 + c];
  }
  float mu = ps / (float)N;
  float var = pq / (float)N - mu * mu;
  float scale = rsqrtf(var + 1e-5f) * pg[c];
  float shift = pbt[c] - mu * scale;
  float wcol[32];
#pragma unroll
  for (int k = 0; k < 32; ++k) wcol[k] = a1w[k * 32 + c];
  float c2c = c2[c];
  const int j = c & 7;
  const int g = c >> 3;
  float w2r[8];
#pragma unroll
  for (int u = 0; u < 8; ++u)
    w2r[u] = (j < 6) ? a2w[(8 * g + u) * 6 + j] : 0.f;
  float bj = (j < 6) ? a2b[j] : 0.f;
  __shared__ float ylds[256];
  __shared__ float alds[256];
  __shared__ float llds[64];
  for (int i = group0; i < N; i += NGROUPS) {
    float y =
        fmaxf(fmaf(scale, __half2float(zh[(size_t)i * 32 + c]), shift), 0.f);
    ylds[tid] = y;
    float a1 = c2c;
    const float4* yp = reinterpret_cast<const float4*>(&ylds[gib * 32]);
#pragma unroll
    for (int kk = 0; kk < 8; ++kk) {
      float4 y4 = yp[kk];
      a1 = fmaf(y4.x, wcol[kk * 4 + 0], a1);
      a1 = fmaf(y4.y, wcol[kk * 4 + 1], a1);
      a1 = fmaf(y4.z, wcol[kk * 4 + 2], a1);
      a1 = fmaf(y4.w, wcol[kk * 4 + 3], a1);
    }
    a1 = fmaxf(a1, 0.f);
    alds[tid] = a1;
    const float4* ap =
        reinterpret_cast<const float4*>(&alds[gib * 32 + g * 8]);
    float4 a4a = ap[0];
    float4 a4b = ap[1];
    float l = a4a.x * w2r[0];
    l = fmaf(a4a.y, w2r[1], l);
    l = fmaf(a4a.z, w2r[2], l);
    l = fmaf(a4a.w, w2r[3], l);
    l = fmaf(a4b.x, w2r[4], l);
    l = fmaf(a4b.y, w2r[5], l);
    l = fmaf(a4b.z, w2r[6], l);
    l = fmaf(a4b.w, w2r[7], l);
    l += __shfl_xor(l, 8, 32);
    l += __shfl_xor(l, 16, 32);
    l += bj;  // j>=6 lanes: l stays exactly 0 (w2r zeros) -> safe pad
    llds[gib * 8 + j] = l;
    const float4* lp = reinterpret_cast<const float4*>(&llds[gib * 8]);
    float4 L0 = lp[0];
    float4 L1 = lp[1];
    float mx =
        fmaxf(fmaxf(fmaxf(L0.x, L0.y), fmaxf(L0.z, L0.w)), fmaxf(L1.x, L1.y));
    float e0 = __expf(L0.x - mx), e1 = __expf(L0.y - mx),
          e2 = __expf(L0.z - mx), e3 = __expf(L0.w - mx),
          e4 = __expf(L1.x - mx), e5 = __expf(L1.y - mx);
    float inv = 1.0f / (e0 + e1 + e2 + e3 + e4 + e5);
    if (c < 6) {
      float v = e0;
      v = (c == 1) ? e1 : v;
      v = (c == 2) ? e2 : v;
      v = (c == 3) ? e3 : v;
      v = (c == 4) ? e4 : v;
      v = (c == 5) ? e5 : v;
      out[(size_t)i * 6 + c] = v * inv;
    }
  }
}

// ---------------------------------------------------------------------------
// fallback kernels (atomic scatter path) — used only if workspace too small
// ---------------------------------------------------------------------------
__global__ __launch_bounds__(256) void edge_d4(
    const int* __restrict__ src, const int* __restrict__ dst,
    const float* __restrict__ ea, const float* __restrict__ x,
    const float* __restrict__ elw, const float* __restrict__ elb,
    float* __restrict__ agg, int E) {
  int e = blockIdx.x * TPB + threadIdx.x;
  if (e >= E) return;
  int s = src[e], d = dst[e];
  float a = ea[e];
  float4 xv = *reinterpret_cast<const float4*>(x + (size_t)s * 4);
  float m0 = fmaxf(xv.x + a * elw[0] + elb[0], 0.0f);
  float m1 = fmaxf(xv.y + a * elw[1] + elb[1], 0.0f);
  float m2 = fmaxf(xv.z + a * elw[2] + elb[2], 0.0f);
  float m3 = fmaxf(xv.w + a * elw[3] + elb[3], 0.0f);
  float* ap = agg + (size_t)d * 32;
  atomicAdd(ap + 0, m0);
  atomicAdd(ap + 1, m1);
  atomicAdd(ap + 2, m2);
  atomicAdd(ap + 3, m3);
}

__global__ __launch_bounds__(256) void edge_d32(
    const int* __restrict__ src, const int* __restrict__ dst,
    const float* __restrict__ ea, const float* __restrict__ x,
    const float* __restrict__ elw, const float* __restrict__ elb,
    float* __restrict__ agg, int E) {
  int tid = blockIdx.x * TPB + threadIdx.x;
  int e = tid >> 5;
  int c = tid & 31;
  if (e >= E) return;
  int s = src[e], d = dst[e];
  float a = ea[e];
  float m = fmaxf(x[(size_t)s * 32 + c] + a * elw[c] + elb[c], 0.0f);
  atomicAdd(agg + (size_t)d * 32 + c, m);
}

template <int DIN>
__global__ __launch_bounds__(256) void node_a(
    const float* __restrict__ x, float* aggz, const float* __restrict__ w,
    const float* __restrict__ b, const float* __restrict__ epsp,
    float* __restrict__ ssum, float* __restrict__ ssq, int N) {
  int i = blockIdx.x * TPB + threadIdx.x;
  float zv[32];
  if (i < N) {
    float one_eps = 1.0f + epsp[0];
    float h[DIN];
    if constexpr (DIN == 4) {
      float4 xv = *reinterpret_cast<const float4*>(x + (size_t)i * 4);
      float4 av = *reinterpret_cast<const float4*>(aggz + (size_t)i * 32);
      h[0] = one_eps * xv.x + av.x;
      h[1] = one_eps * xv.y + av.y;
      h[2] = one_eps * xv.z + av.z;
      h[3] = one_eps * xv.w + av.w;
    } else {
#pragma unroll
      for (int k0 = 0; k0 < 32; k0 += 4) {
        float4 xv = *reinterpret_cast<const float4*>(x + (size_t)i * 32 + k0);
        float4 av =
            *reinterpret_cast<const float4*>(aggz + (size_t)i * 32 + k0);
        h[k0 + 0] = one_eps * xv.x + av.x;
        h[k0 + 1] = one_eps * xv.y + av.y;
        h[k0 + 2] = one_eps * xv.z + av.z;
        h[k0 + 3] = one_eps * xv.w + av.w;
      }
    }
#pragma unroll
    for (int c = 0; c < 32; ++c) zv[c] = b[c];
#pragma unroll
    for (int k = 0; k < DIN; ++k)
#pragma unroll
      for (int c = 0; c < 32; ++c) zv[c] = fmaf(h[k], w[k * 32 + c], zv[c]);
#pragma unroll
    for (int c0 = 0; c0 < 32; c0 += 4) {
      float4 o = make_float4(zv[c0], zv[c0 + 1], zv[c0 + 2], zv[c0 + 3]);
      *reinterpret_cast<float4*>(aggz + (size_t)i * 32 + c0) = o;
    }
  } else {
#pragma unroll
    for (int c = 0; c < 32; ++c) zv[c] = 0.0f;
  }
  __shared__ float ls[32], lq[32];
  if (threadIdx.x < 32) {
    ls[threadIdx.x] = 0.0f;
    lq[threadIdx.x] = 0.0f;
  }
  __syncthreads();
#pragma unroll
  for (int c = 0; c < 32; ++c) {
    float v = zv[c];
    float q = zv[c] * zv[c];
#pragma unroll
    for (int off = 32; off > 0; off >>= 1) {
      v += __shfl_xor(v, off, 64);
      q += __shfl_xor(q, off, 64);
    }
    if ((threadIdx.x & 63) == 0) {
      atomicAdd(&ls[c], v);
      atomicAdd(&lq[c], q);
    }
  }
  __syncthreads();
  if (threadIdx.x < 32) {
    atomicAdd(&ssum[threadIdx.x], ls[threadIdx.x]);
    atomicAdd(&ssq[threadIdx.x], lq[threadIdx.x]);
  }
}

__global__ __launch_bounds__(256) void node_b(
    const float* __restrict__ z, const float* __restrict__ ssum,
    const float* __restrict__ ssq, const float* __restrict__ g,
    const float* __restrict__ bt, float* __restrict__ out, int N) {
  __shared__ float sscale[32], sshift[32];
  if (threadIdx.x < 32) {
    int c = threadIdx.x;
    float mu = ssum[c] / (float)N;
    float var = ssq[c] / (float)N - mu * mu;
    float inv = 1.0f / sqrtf(var + 1e-5f);
    float sc = inv * g[c];
    sscale[c] = sc;
    sshift[c] = bt[c] - mu * sc;
  }
  __syncthreads();
  int i = blockIdx.x * TPB + threadIdx.x;
  if (i >= N) return;
#pragma unroll
  for (int c0 = 0; c0 < 32; c0 += 4) {
    float4 zv = *reinterpret_cast<const float4*>(z + (size_t)i * 32 + c0);
    float4 o;
    o.x = fmaxf(zv.x * sscale[c0 + 0] + sshift[c0 + 0], 0.0f);
    o.y = fmaxf(zv.y * sscale[c0 + 1] + sshift[c0 + 1], 0.0f);
    o.z = fmaxf(zv.z * sscale[c0 + 2] + sshift[c0 + 2], 0.0f);
    o.w = fmaxf(zv.w * sscale[c0 + 3] + sshift[c0 + 3], 0.0f);
    *reinterpret_cast<float4*>(out + (size_t)i * 32 + c0) = o;
  }
}

__global__ __launch_bounds__(256) void node_b3_head(
    const float* __restrict__ z, const float* __restrict__ ssum,
    const float* __restrict__ ssq, const float* __restrict__ g,
    const float* __restrict__ bt, const float* __restrict__ a1w,
    const float* __restrict__ c2, const float* __restrict__ a2w,
    const float* __restrict__ a2b, float* __restrict__ out, int N) {
  __shared__ float sscale[32], sshift[32];
  if (threadIdx.x < 32) {
    int c = threadIdx.x;
    float mu = ssum[c] / (float)N;
    float var = ssq[c] / (float)N - mu * mu;
    float inv = 1.0f / sqrtf(var + 1e-5f);
    float sc = inv * g[c];
    sscale[c] = sc;
    sshift[c] = bt[c] - mu * sc;
  }
  __syncthreads();
  int i = blockIdx.x * TPB + threadIdx.x;
  if (i >= N) return;
  float y[32];
#pragma unroll
  for (int c0 = 0; c0 < 32; c0 += 4) {
    float4 zv = *reinterpret_cast<const float4*>(z + (size_t)i * 32 + c0);
    y[c0 + 0] = fmaxf(zv.x * sscale[c0 + 0] + sshift[c0 + 0], 0.0f);
    y[c0 + 1] = fmaxf(zv.y * sscale[c0 + 1] + sshift[c0 + 1], 0.0f);
    y[c0 + 2] = fmaxf(zv.z * sscale[c0 + 2] + sshift[c0 + 2], 0.0f);
    y[c0 + 3] = fmaxf(zv.w * sscale[c0 + 3] + sshift[c0 + 3], 0.0f);
  }
  float a1[32];
#pragma unroll
  for (int c = 0; c < 32; ++c) a1[c] = c2[c];
#pragma unroll
  for (int k = 0; k < 32; ++k)
#pragma unroll
    for (int c = 0; c < 32; ++c) a1[c] = fmaf(y[k], a1w[k * 32 + c], a1[c]);
#pragma unroll
  for (int c = 0; c < 32; ++c) a1[c] = fmaxf(a1[c], 0.0f);
  float lg[6];
#pragma unroll
  for (int j = 0; j < 6; ++j) lg[j] = a2b[j];
#pragma unroll
  for (int k = 0; k < 32; ++k)
#pragma unroll
    for (int j = 0; j < 6; ++j) lg[j] = fmaf(a1[k], a2w[k * 6 + j], lg[j]);
  float mx = lg[0];
#pragma unroll
  for (int j = 1; j < 6; ++j) mx = fmaxf(mx, lg[j]);
  float s = 0.0f;
#pragma unroll
  for (int j = 0; j < 6; ++j) {
    lg[j] = expf(lg[j] - mx);
    s += lg[j];
  }
  float rs = 1.0f / s;
#pragma unroll
  for (int j = 0; j < 6; ++j) out[(size_t)i * 6 + j] = lg[j] * rs;
}

// ---------------------------------------------------------------------------
extern "C" void kernel_launch(void* const* d_in, const int* in_sizes, int n_in,
                              void* d_out, int out_size, void* d_ws,
                              size_t ws_size, hipStream_t stream) {
  const float* states = (const float*)d_in[0];
  const float* x = (const float*)d_in[1];
  const int* ei = (const int*)d_in[2];
  const float* ea = (const float*)d_in[3];
  const float* eps1 = (const float*)d_in[5];
  const float* elw1 = (const float*)d_in[6];
  const float* elb1 = (const float*)d_in[7];
  const float* w1 = (const float*)d_in[8];
  const float* b1 = (const float*)d_in[9];
  const float* g1 = (const float*)d_in[10];
  const float* bt1 = (const float*)d_in[11];
  const float* eps2 = (const float*)d_in[12];
  const float* elw2 = (const float*)d_in[13];
  const float* elb2 = (const float*)d_in[14];
  const float* w2 = (const float*)d_in[15];
  const float* b2 = (const float*)d_in[16];
  const float* g2 = (const float*)d_in[17];
  const float* bt2 = (const float*)d_in[18];
  const float* eps3 = (const float*)d_in[19];
  const float* elw3 = (const float*)d_in[20];
  const float* elb3 = (const float*)d_in[21];
  const float* w3 = (const float*)d_in[22];
  const float* b3 = (const float*)d_in[23];
  const float* g3 = (const float*)d_in[24];
  const float* bt3 = (const float*)d_in[25];
  const float* sw = (const float*)d_in[26];
  const float* sb = (const float*)d_in[27];
  const float* a1w = (const float*)d_in[28];
  const float* a1b = (const float*)d_in[29];
  const float* a2w = (const float*)d_in[30];
  const float* a2b = (const float*)d_in[31];

  int N = in_sizes[1] / 4;
  int E = in_sizes[3];
  const int* src = ei;
  const int* dst = ei + E;
  float* out = (float*)d_out;

  // workspace layout (CSR path), byte-based:
  //   zhA  : N*32 half (64N bytes)   z1, z3
  //   zhB  : N*32 half (64N bytes)   z2
  //   stats: 1536 f32 ; c2: 32 f32
  //   pe   : E int2 ; rowptr: N+1 ; cursor: N ; bsum: <=512
  char* wsb = (char*)d_ws;
  __half* zhA = (__half*)wsb;
  __half* zhB = (__half*)(wsb + (size_t)64 * N);
  float* stats = (float*)(wsb + (size_t)128 * N);
  float* c2csr = stats + 1536;
  int2* pe = (int2*)(c2csr + 32);
  int* rowptr = (int*)(pe + (size_t)E);
  int* cursor = rowptr + (N + 1);
  int* bsum = cursor + N;

  int nblkN = (N + TPB - 1) / TPB;
  int nblkE = (E + TPB - 1) / TPB;
  int nb = (N + SCAN_CHUNK - 1) / SCAN_CHUNK;

  size_t need = (size_t)128 * N + 6272 + (size_t)8 * E + (size_t)4 * (N + 1) +
                (size_t)4 * N + 2048;

  if (ws_size >= need && nb <= 512) {
    prep_kernel<<<1, TPB, 0, stream>>>(states, sw, sb, a1w, a1b, stats, c2csr,
                                       1536);
    // CSR build (hist/scatter XCD-partitioned by dst range)
    hipMemsetAsync(cursor, 0, (size_t)N * sizeof(int), stream);
    hist3_k<<<NBLK_TEAM, TPB, 0, stream>>>(dst, cursor, E, N);
    scan1_k<<<nb, TPB, 0, stream>>>(cursor, rowptr, bsum, N);
    scan2_k<<<1, 512, 0, stream>>>(bsum, nb);
    scan3_k<<<nblkN, TPB, 0, stream>>>(rowptr, cursor, bsum, N, E);
    scatter3_k<<<NBLK_TEAM, TPB, 0, stream>>>(src, dst, ea, cursor, pe, E, N);

    layer1_k<<<NBLK_LAYER, TPB, 0, stream>>>(rowptr, pe, x, elw1, elb1, w1, b1,
                                             eps1, zhA, stats + 0, N);
    layerH_k<<<NBLK_LAYER, TPB, 0, stream>>>(rowptr, pe, zhA, stats + 0, g1,
                                             bt1, elw2, elb2, w2, b2, eps2,
                                             zhB, stats + 512, N);
    layerH_k<<<NBLK_LAYER, TPB, 0, stream>>>(rowptr, pe, zhB, stats + 512, g2,
                                             bt2, elw3, elb3, w3, b3, eps3,
                                             zhA, stats + 1024, N);
    head_k<<<NBLK_LAYER, TPB, 0, stream>>>(zhA, stats + 1024, g3, bt3, a1w,
                                           c2csr, a2w, a2b, out, N);
  } else {
    // fallback: atomic scatter path (f32 layout over d_ws)
    float* zA = (float*)d_ws;
    float* zB = zA + (size_t)N * 32;
    float* statsFB = zB + (size_t)N * 32;
    float* c2fb = statsFB + 192;
    prep_kernel<<<1, TPB, 0, stream>>>(states, sw, sb, a1w, a1b, statsFB, c2fb,
                                       192);
    size_t aggBytes = (size_t)N * 32 * sizeof(float);
    int nblkE32 = (int)(((long long)E * 32 + TPB - 1) / TPB);
    hipMemsetAsync(zA, 0, aggBytes, stream);
    edge_d4<<<nblkE, TPB, 0, stream>>>(src, dst, ea, x, elw1, elb1, zA, E);
    node_a<4><<<nblkN, TPB, 0, stream>>>(x, zA, w1, b1, eps1, statsFB + 0,
                                         statsFB + 32, N);
    node_b<<<nblkN, TPB, 0, stream>>>(zA, statsFB + 0, statsFB + 32, g1, bt1,
                                      zB, N);
    hipMemsetAsync(zA, 0, aggBytes, stream);
    edge_d32<<<nblkE32, TPB, 0, stream>>>(src, dst, ea, zB, elw2, elb2, zA, E);
    node_a<32><<<nblkN, TPB, 0, stream>>>(zB, zA, w2, b2, eps2, statsFB + 64,
                                          statsFB + 96, N);
    node_b<<<nblkN, TPB, 0, stream>>>(zA, statsFB + 64, statsFB + 96, g2, bt2,
                                      zB, N);
    hipMemsetAsync(zA, 0, aggBytes, stream);
    edge_d32<<<nblkE32, TPB, 0, stream>>>(src, dst, ea, zB, elw3, elb3, zA, E);
    node_a<32><<<nblkN, TPB, 0, stream>>>(zB, zA, w3, b3, eps3, statsFB + 128,
                                          statsFB + 160, N);
    node_b3_head<<<nblkN, TPB, 0, stream>>>(zA, statsFB + 128, statsFB + 160,
                                            g3, bt3, a1w, c2fb, a2w, a2b, out,
                                            N);
  }
}